// Round 1
// baseline (419.630 us; speedup 1.0000x reference)
//
#include <hip/hip_runtime.h>
#include <math.h>

#define T_LEN 4096
#define B_N 64
#define H_N 256
#define Q_N 1024
#define K_F 31
#define PAD 15
#define WL 1024

__device__ __forceinline__ float tanh_fast(float x) {
    // tanh(x) = 1 - 2/(exp(2x)+1); exact at +-inf saturation
    float e = __expf(2.0f * x);
    return 1.0f - 2.0f / (e + 1.0f);
}

// ---------------- K0: q[b][h] = dot(query[b,:], wq[h,:]) + bq[h] + conv_b[h]
__global__ __launch_bounds__(256) void k_query(const float* __restrict__ query,
        const float* __restrict__ wq, const float* __restrict__ bq,
        const float* __restrict__ conv_b, float* __restrict__ qq) {
    int b = blockIdx.x, tid = threadIdx.x;  // tid == h (H_N == 256)
    __shared__ float qv[Q_N];
    for (int i = tid; i < Q_N; i += 256) qv[i] = query[b * Q_N + i];
    __syncthreads();
    const float4* wrow = (const float4*)(wq + (size_t)tid * Q_N);
    float acc = 0.f;
    #pragma unroll 4
    for (int i = 0; i < Q_N / 4; i++) {
        float4 wv = wrow[i];
        float4 q4 = *(const float4*)&qv[i * 4];
        acc += wv.x * q4.x + wv.y * q4.y + wv.z * q4.z + wv.w * q4.w;
    }
    qq[b * H_N + tid] = acc + bq[tid] + conv_b[tid];
}

// ---------------- K1: partial score over a 32-h chunk, all 1024 w
__global__ __launch_bounds__(256) void k_score(
        const float* __restrict__ ca, const int* __restrict__ mask,
        const float* __restrict__ init, const int* __restrict__ wstart,
        const float* __restrict__ conv_w, const float* __restrict__ qq,
        const float* __restrict__ ws_vec, float* __restrict__ scoreP) {
    int hc = blockIdx.x, b = blockIdx.y, tid = threadIdx.x;
    int h0 = hc * 32;
    __shared__ float loc[1056];
    __shared__ float cw[32][32];   // padded col 31 = 0
    __shared__ float qv[32], wv[32];
    int wsb = wstart[b];
    for (int i = tid; i < 1056; i += 256) {
        float v = 0.f;
        if (i < 1054) {
            int p = wsb + i;
            if (p < PAD) v = init[b];
            else {
                int t = p - PAD;
                if (t < T_LEN && mask[b * T_LEN + t] != 0) v = ca[b * T_LEN + t];
            }
        }
        loc[i] = v;
    }
    for (int i = tid; i < 32 * 32; i += 256) {
        int r = i >> 5, c = i & 31;
        cw[r][c] = (c < K_F) ? conv_w[(h0 + r) * K_F + c] : 0.f;
    }
    if (tid < 32) { qv[tid] = qq[b * H_N + h0 + tid]; wv[tid] = ws_vec[h0 + tid]; }
    __syncthreads();

    int w0 = tid * 4;                 // 4 consecutive w per thread
    float l[35];
    #pragma unroll
    for (int j = 0; j < 35; j++) l[j] = loc[w0 + j];

    float s0 = 0.f, s1 = 0.f, s2 = 0.f, s3 = 0.f;
    for (int hh = 0; hh < 32; hh++) {
        float bias = qv[hh];
        float c0 = bias, c1 = bias, c2 = bias, c3 = bias;
        #pragma unroll
        for (int k = 0; k < 32; k += 4) {
            float4 cq = *(const float4*)&cw[hh][k];
            c0 += l[k + 0] * cq.x; c1 += l[k + 1] * cq.x; c2 += l[k + 2] * cq.x; c3 += l[k + 3] * cq.x;
            c0 += l[k + 1] * cq.y; c1 += l[k + 2] * cq.y; c2 += l[k + 3] * cq.y; c3 += l[k + 4] * cq.y;
            c0 += l[k + 2] * cq.z; c1 += l[k + 3] * cq.z; c2 += l[k + 4] * cq.z; c3 += l[k + 5] * cq.z;
            c0 += l[k + 3] * cq.w; c1 += l[k + 4] * cq.w; c2 += l[k + 5] * cq.w; c3 += l[k + 6] * cq.w;
        }
        float wh = wv[hh];
        s0 += wh * tanh_fast(c0); s1 += wh * tanh_fast(c1);
        s2 += wh * tanh_fast(c2); s3 += wh * tanh_fast(c3);
    }
    float4 o = make_float4(s0, s1, s2, s3);
    *(float4*)&scoreP[((size_t)hc * B_N + b) * WL + w0] = o;
}

// ---------------- K2a: per-batch softmax, argmax, scatter outputs, zero ctx
__global__ __launch_bounds__(256) void k_softmax(
        const float* __restrict__ scoreP, const int* __restrict__ mask,
        const float* __restrict__ ca, const int* __restrict__ wstart,
        const int* __restrict__ num_tokens, float* __restrict__ alignW,
        float* __restrict__ out_ctx, float* __restrict__ out_cum,
        float* __restrict__ out_align, float* __restrict__ out_nws) {
    int b = blockIdx.x, tid = threadIdx.x;
    __shared__ float sc[WL];
    __shared__ float red[256];
    __shared__ int redi[256];
    int wsb = wstart[b];
    for (int w = tid; w < WL; w += 256) {
        float s = 0.f;
        #pragma unroll
        for (int p = 0; p < 8; p++) s += scoreP[((size_t)p * B_N + b) * WL + w];
        if (mask[b * T_LEN + wsb + w] == 0) s = -3.0e38f;
        sc[w] = s;
    }
    __syncthreads();
    float mx = -3.0e38f;
    for (int w = tid; w < WL; w += 256) mx = fmaxf(mx, sc[w]);
    red[tid] = mx; __syncthreads();
    for (int s = 128; s > 0; s >>= 1) {
        if (tid < s) red[tid] = fmaxf(red[tid], red[tid + s]);
        __syncthreads();
    }
    mx = red[0]; __syncthreads();
    float lsum = 0.f;
    for (int w = tid; w < WL; w += 256) {
        float e = __expf(sc[w] - mx);
        sc[w] = e; lsum += e;
    }
    red[tid] = lsum; __syncthreads();
    for (int s = 128; s > 0; s >>= 1) {
        if (tid < s) red[tid] += red[tid + s];
        __syncthreads();
    }
    float inv = 1.0f / red[0];
    __syncthreads();
    float bv = -1.f; int bi = 0;
    for (int w = tid; w < WL; w += 256) {   // ascending w per thread: strict > keeps first tie
        float a = sc[w] * inv;
        sc[w] = a;
        alignW[b * WL + w] = a;
        if (a > bv) { bv = a; bi = w; }
    }
    red[tid] = bv; redi[tid] = bi; __syncthreads();
    for (int s = 128; s > 0; s >>= 1) {
        if (tid < s) {
            float ov = red[tid + s]; int oi = redi[tid + s];
            if (ov > red[tid] || (ov == red[tid] && oi < redi[tid])) { red[tid] = ov; redi[tid] = oi; }
        }
        __syncthreads();
    }
    if (tid == 0) {
        int tstar = wsb + redi[0];
        int nws = tstar - WL / 2;
        int lim = num_tokens[b] - WL;
        nws = nws < lim ? nws : lim;
        nws = nws > 0 ? nws : 0;
        out_nws[b] = (float)nws;
    }
    for (int t = tid; t < T_LEN; t += 256) {
        int j = t - wsb;
        float av = (j >= 0 && j < WL) ? sc[j] : 0.f;
        float cav = (mask[b * T_LEN + t] != 0) ? ca[b * T_LEN + t] : 0.f;
        out_align[b * T_LEN + t] = av;
        out_cum[b * T_LEN + t] = cav + av;
    }
    out_ctx[b * H_N + tid] = 0.f;   // 256 threads == H_N
}

// ---------------- K2b: context[b,h] += sum_w align*tokens (64-w chunk/block)
__global__ __launch_bounds__(256) void k_context(
        const float* __restrict__ tokens, const float* __restrict__ alignW,
        const int* __restrict__ wstart, float* __restrict__ out_ctx) {
    int wc = blockIdx.x, b = blockIdx.y, tid = threadIdx.x;  // tid == h
    __shared__ float av[64];
    if (tid < 64) av[tid] = alignW[b * WL + wc * 64 + tid];
    __syncthreads();
    int wsb = wstart[b];
    const float* tok = tokens + ((size_t)(wsb + wc * 64) * B_N + b) * H_N + tid;
    float acc = 0.f;
    #pragma unroll 4
    for (int j = 0; j < 64; j++) {
        acc += av[j] * tok[(size_t)j * B_N * H_N];
    }
    atomicAdd(&out_ctx[b * H_N + tid], acc);
}

extern "C" void kernel_launch(void* const* d_in, const int* in_sizes, int n_in,
                              void* d_out, int out_size, void* d_ws, size_t ws_size,
                              hipStream_t stream) {
    const float* tokens     = (const float*)d_in[0];
    const int*   mask       = (const int*)  d_in[1];
    const int*   num_tokens = (const int*)  d_in[2];
    const float* query      = (const float*)d_in[3];   // (1,B,Q) -> base is query[0]
    const float* ca         = (const float*)d_in[4];
    const float* init       = (const float*)d_in[5];
    const int*   wstart     = (const int*)  d_in[6];
    const float* conv_w     = (const float*)d_in[7];
    const float* conv_b     = (const float*)d_in[8];
    const float* wq         = (const float*)d_in[9];
    const float* bq         = (const float*)d_in[10];
    const float* ws_vec     = (const float*)d_in[11];

    float* out       = (float*)d_out;
    float* out_ctx   = out;                          // B*H   = 16384
    float* out_cum   = out + 16384;                  // B*T   = 262144
    float* out_align = out + 16384 + 262144;         // B*T   = 262144
    float* out_nws   = out + 16384 + 2 * 262144;     // B     = 64 (as float)

    float* scoreP = (float*)d_ws;                    // 8*B*WL floats = 2MB
    float* qq     = scoreP + 8 * B_N * WL;           // B*H
    float* alignW = qq + B_N * H_N;                  // B*WL

    k_query  <<<dim3(B_N),      dim3(256), 0, stream>>>(query, wq, bq, conv_b, qq);
    k_score  <<<dim3(8, B_N),   dim3(256), 0, stream>>>(ca, mask, init, wstart, conv_w, qq, ws_vec, scoreP);
    k_softmax<<<dim3(B_N),      dim3(256), 0, stream>>>(scoreP, mask, ca, wstart, num_tokens, alignW,
                                                        out_ctx, out_cum, out_align, out_nws);
    k_context<<<dim3(16, B_N),  dim3(256), 0, stream>>>(tokens, alignW, wstart, out_ctx);
}

// Round 2
// 377.100 us; speedup vs baseline: 1.1128x; 1.1128x over previous
//
#include <hip/hip_runtime.h>
#include <math.h>

#define T_LEN 4096
#define B_N 64
#define H_N 256
#define Q_N 1024
#define K_F 31
#define PAD 15
#define WL 1024

__device__ __forceinline__ float tanh_fast(float x) {
    // tanh(x) = 1 - 2/(exp(2x)+1); exact at +-inf saturation
    float e = __expf(2.0f * x);
    return 1.0f - 2.0f / (e + 1.0f);
}

// ---------------- K1: fused query-GEMV + conv + tanh + partial score
// grid (8, B): block handles h-chunk hc (32 h) for batch b, all 1024 w.
__global__ __launch_bounds__(256) void k_score(
        const float* __restrict__ query, const float* __restrict__ wq,
        const float* __restrict__ bq, const float* __restrict__ conv_b,
        const float* __restrict__ ca, const int* __restrict__ mask,
        const float* __restrict__ init, const int* __restrict__ wstart,
        const float* __restrict__ conv_w, const float* __restrict__ ws_vec,
        float* __restrict__ scoreP) {
    int hc = blockIdx.x, b = blockIdx.y, tid = threadIdx.x;
    int h0 = hc * 32;
    __shared__ __align__(16) float qbuf[Q_N];
    __shared__ __align__(16) float loc[1056];
    __shared__ __align__(16) float cw[32][32];   // padded cols 31.. = 0
    __shared__ float qv[32], wv[32];
    int wsb = wstart[b];

    for (int i = tid; i < Q_N; i += 256) qbuf[i] = query[b * Q_N + i];
    for (int i = tid; i < 1056; i += 256) {
        float v = 0.f;
        if (i < 1054) {
            int p = wsb + i;
            if (p < PAD) v = init[b];
            else {
                int t = p - PAD;
                if (t < T_LEN && mask[b * T_LEN + t] != 0) v = ca[b * T_LEN + t];
            }
        }
        loc[i] = v;
    }
    for (int i = tid; i < 32 * 32; i += 256) {
        int r = i >> 5, c = i & 31;
        cw[r][c] = (c < K_F) ? conv_w[(h0 + r) * K_F + c] : 0.f;
    }
    if (tid < 32) wv[tid] = ws_vec[h0 + tid];
    __syncthreads();

    // q[h] = dot(query[b,:], wq[h0+h,:]) + bq + conv_b ; 8 threads per h-row
    {
        int h = tid >> 3, part = tid & 7;
        const float4* wrow = (const float4*)(wq + (size_t)(h0 + h) * Q_N) + part * 32;
        const float4* qrow = (const float4*)qbuf + part * 32;
        float acc = 0.f;
        #pragma unroll 8
        for (int i = 0; i < 32; i++) {
            float4 a = wrow[i], c = qrow[i];
            acc += a.x * c.x + a.y * c.y + a.z * c.z + a.w * c.w;
        }
        acc += __shfl_xor(acc, 1);
        acc += __shfl_xor(acc, 2);
        acc += __shfl_xor(acc, 4);
        if (part == 0) qv[h] = acc + bq[h0 + h] + conv_b[h0 + h];
    }
    __syncthreads();

    int w0 = tid * 4;                 // 4 consecutive w per thread
    float l[35];
    #pragma unroll
    for (int j = 0; j < 35; j++) l[j] = loc[w0 + j];

    float s0 = 0.f, s1 = 0.f, s2 = 0.f, s3 = 0.f;
    for (int hh = 0; hh < 32; hh++) {
        float bias = qv[hh];
        float c0 = bias, c1 = bias, c2 = bias, c3 = bias;
        #pragma unroll
        for (int k = 0; k < 32; k += 4) {
            float4 cq = *(const float4*)&cw[hh][k];
            c0 += l[k + 0] * cq.x; c1 += l[k + 1] * cq.x; c2 += l[k + 2] * cq.x; c3 += l[k + 3] * cq.x;
            c0 += l[k + 1] * cq.y; c1 += l[k + 2] * cq.y; c2 += l[k + 3] * cq.y; c3 += l[k + 4] * cq.y;
            c0 += l[k + 2] * cq.z; c1 += l[k + 3] * cq.z; c2 += l[k + 4] * cq.z; c3 += l[k + 5] * cq.z;
            c0 += l[k + 3] * cq.w; c1 += l[k + 4] * cq.w; c2 += l[k + 5] * cq.w; c3 += l[k + 6] * cq.w;
        }
        float wh = wv[hh];
        s0 += wh * tanh_fast(c0); s1 += wh * tanh_fast(c1);
        s2 += wh * tanh_fast(c2); s3 += wh * tanh_fast(c3);
    }
    *(float4*)&scoreP[((size_t)hc * B_N + b) * WL + w0] = make_float4(s0, s1, s2, s3);
}

// ---------------- K2: per-batch softmax, argmax, scatter outputs, zero ctx
__global__ __launch_bounds__(256) void k_softmax(
        const float* __restrict__ scoreP, const int* __restrict__ mask,
        const float* __restrict__ ca, const int* __restrict__ wstart,
        const int* __restrict__ num_tokens, float* __restrict__ alignW,
        float* __restrict__ out_ctx, float* __restrict__ out_cum,
        float* __restrict__ out_align, float* __restrict__ out_nws) {
    int b = blockIdx.x, tid = threadIdx.x;
    __shared__ float sc[WL];
    __shared__ float red[256];
    __shared__ int redi[256];
    int wsb = wstart[b];
    for (int w = tid; w < WL; w += 256) {
        float s = 0.f;
        #pragma unroll
        for (int p = 0; p < 8; p++) s += scoreP[((size_t)p * B_N + b) * WL + w];
        if (mask[b * T_LEN + wsb + w] == 0) s = -3.0e38f;
        sc[w] = s;
    }
    __syncthreads();
    float mx = -3.0e38f;
    for (int w = tid; w < WL; w += 256) mx = fmaxf(mx, sc[w]);
    red[tid] = mx; __syncthreads();
    for (int s = 128; s > 0; s >>= 1) {
        if (tid < s) red[tid] = fmaxf(red[tid], red[tid + s]);
        __syncthreads();
    }
    mx = red[0]; __syncthreads();
    float lsum = 0.f;
    for (int w = tid; w < WL; w += 256) {
        float e = __expf(sc[w] - mx);
        sc[w] = e; lsum += e;
    }
    red[tid] = lsum; __syncthreads();
    for (int s = 128; s > 0; s >>= 1) {
        if (tid < s) red[tid] += red[tid + s];
        __syncthreads();
    }
    float inv = 1.0f / red[0];
    __syncthreads();
    float bv = -1.f; int bi = 0;
    for (int w = tid; w < WL; w += 256) {   // ascending w per thread: strict > keeps first tie
        float a = sc[w] * inv;
        sc[w] = a;
        alignW[b * WL + w] = a;
        if (a > bv) { bv = a; bi = w; }
    }
    red[tid] = bv; redi[tid] = bi; __syncthreads();
    for (int s = 128; s > 0; s >>= 1) {
        if (tid < s) {
            float ov = red[tid + s]; int oi = redi[tid + s];
            if (ov > red[tid] || (ov == red[tid] && oi < redi[tid])) { red[tid] = ov; redi[tid] = oi; }
        }
        __syncthreads();
    }
    if (tid == 0) {
        int tstar = wsb + redi[0];
        int nws = tstar - WL / 2;
        int lim = num_tokens[b] - WL;
        nws = nws < lim ? nws : lim;
        nws = nws > 0 ? nws : 0;
        out_nws[b] = (float)nws;
    }
    // vectorized scatter of alignment_full and cum over T
    const int4* m4p = (const int4*)(mask + (size_t)b * T_LEN);
    const float4* c4p = (const float4*)(ca + (size_t)b * T_LEN);
    float4* oa4 = (float4*)(out_align + (size_t)b * T_LEN);
    float4* oc4 = (float4*)(out_cum + (size_t)b * T_LEN);
    for (int t4 = tid; t4 < T_LEN / 4; t4 += 256) {
        int t = t4 * 4;
        int4 m4 = m4p[t4];
        float4 c4 = c4p[t4];
        float4 av, cum;
        int j0 = t - wsb;
        av.x = (j0 >= 0 && j0 < WL) ? sc[j0] : 0.f;
        av.y = (j0 + 1 >= 0 && j0 + 1 < WL) ? sc[j0 + 1] : 0.f;
        av.z = (j0 + 2 >= 0 && j0 + 2 < WL) ? sc[j0 + 2] : 0.f;
        av.w = (j0 + 3 >= 0 && j0 + 3 < WL) ? sc[j0 + 3] : 0.f;
        cum.x = (m4.x != 0 ? c4.x : 0.f) + av.x;
        cum.y = (m4.y != 0 ? c4.y : 0.f) + av.y;
        cum.z = (m4.z != 0 ? c4.z : 0.f) + av.z;
        cum.w = (m4.w != 0 ? c4.w : 0.f) + av.w;
        oa4[t4] = av;
        oc4[t4] = cum;
    }
    out_ctx[b * H_N + tid] = 0.f;   // 256 threads == H_N
}

// ---------------- K3: context[b,h] += sum_w align*tokens (64-w chunk/block)
// thread t: h-quad (t&63)*4, w-subgroup wj = t>>6 (4 subgroups x 16 rows)
__global__ __launch_bounds__(256) void k_context(
        const float* __restrict__ tokens, const float* __restrict__ alignW,
        const int* __restrict__ wstart, float* __restrict__ out_ctx) {
    int wc = blockIdx.x, b = blockIdx.y, tid = threadIdx.x;
    __shared__ float av[64];
    __shared__ __align__(16) float4 red4[256];
    if (tid < 64) av[tid] = alignW[b * WL + wc * 64 + tid];
    __syncthreads();
    int h4 = (tid & 63) * 4, wj = tid >> 6;
    int wsb = wstart[b];
    const float* tokbase = tokens + ((size_t)(wsb + wc * 64 + wj) * B_N + b) * H_N + h4;
    float4 acc = make_float4(0.f, 0.f, 0.f, 0.f);
    #pragma unroll 4
    for (int j = 0; j < 16; j++) {
        float a = av[wj + 4 * j];
        float4 t4 = *(const float4*)(tokbase + (size_t)(4 * j) * B_N * H_N);
        acc.x += a * t4.x; acc.y += a * t4.y; acc.z += a * t4.z; acc.w += a * t4.w;
    }
    red4[tid] = acc;
    __syncthreads();
    if (tid < 64) {
        float4 r0 = red4[tid], r1 = red4[tid + 64], r2 = red4[tid + 128], r3 = red4[tid + 192];
        float* dst = &out_ctx[b * H_N + tid * 4];
        atomicAdd(dst + 0, r0.x + r1.x + r2.x + r3.x);
        atomicAdd(dst + 1, r0.y + r1.y + r2.y + r3.y);
        atomicAdd(dst + 2, r0.z + r1.z + r2.z + r3.z);
        atomicAdd(dst + 3, r0.w + r1.w + r2.w + r3.w);
    }
}

extern "C" void kernel_launch(void* const* d_in, const int* in_sizes, int n_in,
                              void* d_out, int out_size, void* d_ws, size_t ws_size,
                              hipStream_t stream) {
    const float* tokens     = (const float*)d_in[0];
    const int*   mask       = (const int*)  d_in[1];
    const int*   num_tokens = (const int*)  d_in[2];
    const float* query      = (const float*)d_in[3];   // (1,B,Q) -> base is query[0]
    const float* ca         = (const float*)d_in[4];
    const float* init       = (const float*)d_in[5];
    const int*   wstart     = (const int*)  d_in[6];
    const float* conv_w     = (const float*)d_in[7];
    const float* conv_b     = (const float*)d_in[8];
    const float* wq         = (const float*)d_in[9];
    const float* bq         = (const float*)d_in[10];
    const float* ws_vec     = (const float*)d_in[11];

    float* out       = (float*)d_out;
    float* out_ctx   = out;                          // B*H   = 16384
    float* out_cum   = out + 16384;                  // B*T   = 262144
    float* out_align = out + 16384 + 262144;         // B*T   = 262144
    float* out_nws   = out + 16384 + 2 * 262144;     // B     = 64 (as float)

    float* scoreP = (float*)d_ws;                    // 8*B*WL floats = 2MB
    float* alignW = scoreP + 8 * B_N * WL;           // B*WL

    k_score  <<<dim3(8, B_N),   dim3(256), 0, stream>>>(query, wq, bq, conv_b, ca, mask, init,
                                                        wstart, conv_w, ws_vec, scoreP);
    k_softmax<<<dim3(B_N),      dim3(256), 0, stream>>>(scoreP, mask, ca, wstart, num_tokens, alignW,
                                                        out_ctx, out_cum, out_align, out_nws);
    k_context<<<dim3(16, B_N),  dim3(256), 0, stream>>>(tokens, alignW, wstart, out_ctx);
}